// Round 2
// baseline (488.794 us; speedup 1.0000x reference)
//
#include <hip/hip_runtime.h>
#include <math.h>

#define NB 8
#define NA 1024
#define NN 64
#define NF 128
#define NS 64
#define CUTOFF 5.0f
#define LN2 0.69314718055994530942f

__device__ __forceinline__ float ssp(float x) {
    // softplus(x) - ln2, numerically stable
    return fmaxf(x, 0.0f) + __logf(1.0f + __expf(-fabsf(x))) - LN2;
}

// ---------------- kernel 1: y = x @ W_in2f (no bias) ----------------
__global__ __launch_bounds__(256) void k_in2f(const float* __restrict__ x,
                                              const float* __restrict__ W,
                                              float* __restrict__ y) {
    int g = threadIdx.x & 127;
    int half = threadIdx.x >> 7;
    int row0 = blockIdx.x * 32 + half * 16;
    float acc[16];
#pragma unroll
    for (int i = 0; i < 16; i++) acc[i] = 0.0f;
    for (int k = 0; k < NF; k += 4) {
        float w0 = W[(k + 0) * NF + g];
        float w1 = W[(k + 1) * NF + g];
        float w2 = W[(k + 2) * NF + g];
        float w3 = W[(k + 3) * NF + g];
#pragma unroll
        for (int i = 0; i < 16; i++) {
            float4 xv = *(const float4*)&x[(size_t)(row0 + i) * NF + k];
            acc[i] = fmaf(xv.x, w0, fmaf(xv.y, w1, fmaf(xv.z, w2, fmaf(xv.w, w3, acc[i]))));
        }
    }
#pragma unroll
    for (int i = 0; i < 16; i++) y[(size_t)(row0 + i) * NF + g] = acc[i];
}

// ---------------- kernel 2: filter net + cfconv aggregation ----------------
// one block per (b,a); 256 threads = (g in 0..127) x (n-half in 0..1)
__global__ __launch_bounds__(256) void k_conv(
        const float* __restrict__ fij, const float* __restrict__ rij,
        const int* __restrict__ nbr, const int* __restrict__ nmask,
        const float* __restrict__ y,
        const float* __restrict__ W1, const float* __restrict__ b1,
        const float* __restrict__ W2, const float* __restrict__ b2,
        float* __restrict__ agg) {
    __shared__ float fijT[NS * NN];   // [s][n]  16 KB
    __shared__ float hT[NF * NN];     // [f][n]  32 KB
    __shared__ float mL[NN];
    __shared__ int   iL[NN];
    __shared__ float red[2 * NF];

    int t = threadIdx.x;
    int ba = blockIdx.x;
    int b = ba >> 10;

    // stage f_ij[b,a] transposed into LDS
    const float* fsrc = fij + (size_t)ba * NN * NS;
#pragma unroll
    for (int j = 0; j < 4; j++) {
        int lin = t + j * 256;        // float4 index (1024 total)
        int off = lin * 4;
        int n = off >> 6;             // / NS
        int s = off & 63;
        float4 v = *(const float4*)&fsrc[off];
        fijT[(s + 0) * NN + n] = v.x;
        fijT[(s + 1) * NN + n] = v.y;
        fijT[(s + 2) * NN + n] = v.z;
        fijT[(s + 3) * NN + n] = v.w;
    }
    if (t < NN) {
        float r = rij[(size_t)ba * NN + t];
        int mk = nmask[(size_t)ba * NN + t];   // bool stored as int32
        mL[t] = (mk != 0 && r <= CUTOFF) ? 1.0f : 0.0f;
        iL[t] = nbr[(size_t)ba * NN + t];
    }
    __syncthreads();

    int g = t & 127;          // feature index (also serves as f for phase 2)
    int nh = t >> 7;          // which 32 neighbors this thread owns
    int n0 = nh * 32;

    float acc[32];

    // phase 2: h[n][g] = ssp( sum_s fij[n][s] * W1[s][g] + b1[g] )
    float b1f = b1[g];
#pragma unroll
    for (int i = 0; i < 32; i++) acc[i] = b1f;
    for (int s = 0; s < NS; s++) {
        float w = W1[s * NF + g];
        const float4* fp = (const float4*)&fijT[s * NN + n0];
#pragma unroll
        for (int q = 0; q < 8; q++) {
            float4 v = fp[q];
            acc[q * 4 + 0] = fmaf(v.x, w, acc[q * 4 + 0]);
            acc[q * 4 + 1] = fmaf(v.y, w, acc[q * 4 + 1]);
            acc[q * 4 + 2] = fmaf(v.z, w, acc[q * 4 + 2]);
            acc[q * 4 + 3] = fmaf(v.w, w, acc[q * 4 + 3]);
        }
    }
    {
        float4* hp = (float4*)&hT[g * NN + n0];
#pragma unroll
        for (int q = 0; q < 8; q++) {
            float4 v;
            v.x = ssp(acc[q * 4 + 0]);
            v.y = ssp(acc[q * 4 + 1]);
            v.z = ssp(acc[q * 4 + 2]);
            v.w = ssp(acc[q * 4 + 3]);
            hp[q] = v;
        }
    }
    __syncthreads();

    // phase 3: wf[n] = sum_f h[n][f] * W2[f][g]   (b2 added in epilogue)
    float b2g = b2[g];
#pragma unroll
    for (int i = 0; i < 32; i++) acc[i] = 0.0f;
    for (int f = 0; f < NF; f++) {
        float w = W2[f * NF + g];
        const float4* qp = (const float4*)&hT[f * NN + n0];
#pragma unroll
        for (int q = 0; q < 8; q++) {
            float4 v = qp[q];
            acc[q * 4 + 0] = fmaf(v.x, w, acc[q * 4 + 0]);
            acc[q * 4 + 1] = fmaf(v.y, w, acc[q * 4 + 1]);
            acc[q * 4 + 2] = fmaf(v.z, w, acc[q * 4 + 2]);
            acc[q * 4 + 3] = fmaf(v.w, w, acc[q * 4 + 3]);
        }
    }

    // epilogue: gather y rows, mask, reduce over this thread's 32 neighbors
    const float* yb = y + (size_t)b * NA * NF;
    float local = 0.0f;
#pragma unroll
    for (int i = 0; i < 32; i++) {
        int n = n0 + i;
        if (mL[n] != 0.0f) {                    // wave-uniform branch
            float wf = acc[i] + b2g;
            local = fmaf(yb[(size_t)iL[n] * NF + g], wf, local);
        }
    }
    red[nh * NF + g] = local;
    __syncthreads();
    if (t < NF) {
        agg[(size_t)ba * NF + t] = red[t] + red[NF + t];
    }
}

// ---------------- kernel 3: out = ssp(agg@Wf2+bf2) @ Wd + bd, in place ----------------
__global__ __launch_bounds__(256) void k_out(float* buf,
                                             const float* __restrict__ Wf2,
                                             const float* __restrict__ bf2,
                                             const float* __restrict__ Wd,
                                             const float* __restrict__ bd) {
    __shared__ float vL[32 * NF];   // 16 KB
    int g = threadIdx.x & 127;
    int half = threadIdx.x >> 7;
    int row0 = blockIdx.x * 32 + half * 16;
    float acc[16];

    float bb = bf2[g];
#pragma unroll
    for (int i = 0; i < 16; i++) acc[i] = bb;
    for (int f = 0; f < NF; f += 4) {
        float w0 = Wf2[(f + 0) * NF + g];
        float w1 = Wf2[(f + 1) * NF + g];
        float w2 = Wf2[(f + 2) * NF + g];
        float w3 = Wf2[(f + 3) * NF + g];
#pragma unroll
        for (int i = 0; i < 16; i++) {
            float4 av = *(const float4*)&buf[(size_t)(row0 + i) * NF + f];
            acc[i] = fmaf(av.x, w0, fmaf(av.y, w1, fmaf(av.z, w2, fmaf(av.w, w3, acc[i]))));
        }
    }
#pragma unroll
    for (int i = 0; i < 16; i++) vL[(half * 16 + i) * NF + g] = ssp(acc[i]);
    __syncthreads();

    float bb2 = bd[g];
#pragma unroll
    for (int i = 0; i < 16; i++) acc[i] = bb2;
    for (int f = 0; f < NF; f += 4) {
        float w0 = Wd[(f + 0) * NF + g];
        float w1 = Wd[(f + 1) * NF + g];
        float w2 = Wd[(f + 2) * NF + g];
        float w3 = Wd[(f + 3) * NF + g];
#pragma unroll
        for (int i = 0; i < 16; i++) {
            float4 vv = *(const float4*)&vL[(half * 16 + i) * NF + f];
            acc[i] = fmaf(vv.x, w0, fmaf(vv.y, w1, fmaf(vv.z, w2, fmaf(vv.w, w3, acc[i]))));
        }
    }
#pragma unroll
    for (int i = 0; i < 16; i++) buf[(size_t)(row0 + i) * NF + g] = acc[i];
}

extern "C" void kernel_launch(void* const* d_in, const int* in_sizes, int n_in,
                              void* d_out, int out_size, void* d_ws, size_t ws_size,
                              hipStream_t stream) {
    const float* x    = (const float*)d_in[0];
    const float* rij  = (const float*)d_in[1];
    const float* fij  = (const float*)d_in[2];
    const int*   nbr  = (const int*)d_in[3];
    const int*   nmask = (const int*)d_in[4];     // bool -> int32 per harness
    const float* W_in2f = (const float*)d_in[5];
    const float* W1   = (const float*)d_in[6];
    const float* b1   = (const float*)d_in[7];
    const float* W2   = (const float*)d_in[8];
    const float* b2   = (const float*)d_in[9];
    const float* Wf2  = (const float*)d_in[10];
    const float* bf2  = (const float*)d_in[11];
    const float* Wd   = (const float*)d_in[12];
    const float* bd   = (const float*)d_in[13];

    float* out = (float*)d_out;
    float* y   = (float*)d_ws;                  // 8192*128 f32 = 4 MB scratch

    const int rows = NB * NA;                   // 8192

    k_in2f<<<rows / 32, 256, 0, stream>>>(x, W_in2f, y);
    k_conv<<<rows, 256, 0, stream>>>(fij, rij, nbr, nmask, y, W1, b1, W2, b2, out);
    k_out<<<rows / 32, 256, 0, stream>>>(out, Wf2, bf2, Wd, bd);
}

// Round 3
// 156.465 us; speedup vs baseline: 3.1240x; 3.1240x over previous
//
#include <hip/hip_runtime.h>
#include <math.h>

#define NB 8
#define NA 1024
#define NN 64
#define NF 128
#define NS 64
#define LN2 0.69314718055994530942f
#define HSTR 136   // padded LDS stride (bf16 elems): 272B rows -> conflict-free b128 reads

typedef __attribute__((ext_vector_type(8))) short bf16x8;
typedef __attribute__((ext_vector_type(4))) float f32x4;

__device__ __forceinline__ float ssp(float x) {
    return fmaxf(x, 0.0f) + __logf(1.0f + __expf(-fabsf(x))) - LN2;
}
__device__ __forceinline__ short f2bf(float f) {      // RNE f32 -> bf16
    unsigned u = __float_as_uint(f);
    u += 0x7fffu + ((u >> 16) & 1u);
    return (short)(u >> 16);
}
__device__ __forceinline__ float bf2f(short s) {
    return __uint_as_float(((unsigned)(unsigned short)s) << 16);
}

// ---------------- prep: swizzle W1,W2 into MFMA B-fragment order (bf16) ----------------
// B-frag for 16x16x32: lane l holds B[k=(l>>4)*8+j][col=l&15]; tile (kt,ntg) is 64 lanes x 8 bf16.
__global__ __launch_bounds__(256) void k_prep(const float* __restrict__ W1,
                                              const float* __restrict__ W2,
                                              short* __restrict__ W1f,
                                              short* __restrict__ W2f) {
    int t = blockIdx.x * 256 + threadIdx.x;
    if (t < NS * NF) {
        int k = t >> 7, n = t & 127;
        int kt = k >> 5, lg = (k >> 3) & 3, j = k & 7, ntg = n >> 4, col = n & 15;
        W1f[((kt * 8 + ntg) * 64 + (lg * 16 + col)) * 8 + j] = f2bf(W1[t]);
    }
    if (t < NF * NF) {
        int k = t >> 7, n = t & 127;
        int kt = k >> 5, lg = (k >> 3) & 3, j = k & 7, ntg = n >> 4, col = n & 15;
        W2f[((kt * 8 + ntg) * 64 + (lg * 16 + col)) * 8 + j] = f2bf(W2[t]);
    }
}

// ---------------- kernel 1: y = x @ W_in2f (no bias), f32 ----------------
__global__ __launch_bounds__(256) void k_in2f(const float* __restrict__ x,
                                              const float* __restrict__ W,
                                              float* __restrict__ y) {
    int g = threadIdx.x & 127;
    int half = threadIdx.x >> 7;
    int row0 = blockIdx.x * 32 + half * 16;
    float acc[16];
#pragma unroll
    for (int i = 0; i < 16; i++) acc[i] = 0.0f;
    for (int k = 0; k < NF; k += 4) {
        float w0 = W[(k + 0) * NF + g];
        float w1 = W[(k + 1) * NF + g];
        float w2 = W[(k + 2) * NF + g];
        float w3 = W[(k + 3) * NF + g];
#pragma unroll
        for (int i = 0; i < 16; i++) {
            float4 xv = *(const float4*)&x[(size_t)(row0 + i) * NF + k];
            acc[i] = fmaf(xv.x, w0, fmaf(xv.y, w1, fmaf(xv.z, w2, fmaf(xv.w, w3, acc[i]))));
        }
    }
#pragma unroll
    for (int i = 0; i < 16; i++) y[(size_t)(row0 + i) * NF + g] = acc[i];
}

// ---------------- kernel 2: MFMA filter net + cfconv aggregation ----------------
// one block per (b,a); 4 waves, wave wid owns g-slice [wid*32, wid*32+32)
__global__ __launch_bounds__(256) void k_conv(
        const float* __restrict__ fij, const float* __restrict__ rij,
        const int* __restrict__ nbr, const int* __restrict__ nmask,
        const float* __restrict__ y,
        const short* __restrict__ W1f, const float* __restrict__ b1,
        const short* __restrict__ W2f, const float* __restrict__ b2,
        float* __restrict__ agg) {
    __shared__ short hL[NN * HSTR];   // 17408 B; h (bf16), later reused for masked Wfilt
    __shared__ float mL[NN];
    __shared__ int   iL[NN];
    __shared__ float red[2 * NF];

    int t = threadIdx.x;
    int ba = blockIdx.x;
    int b = ba >> 10;
    int lane = t & 63;
    int wid = t >> 6;

    if (t < NN) {
        float r = rij[(size_t)ba * NN + t];
        int mk = nmask[(size_t)ba * NN + t];
        mL[t] = (mk != 0 && r <= 5.0f) ? 1.0f : 0.0f;
        iL[t] = nbr[(size_t)ba * NN + t];
    }

    const float* fsrc = fij + (size_t)ba * NN * NS;
    int rowA = lane & 15;     // A-frag row within 16
    int kgrp = lane >> 4;     // k-group 0..3
    int goff = wid * 32;

    int gc0 = goff + (lane & 15);
    int gc1 = gc0 + 16;
    float b1v0 = b1[gc0], b1v1 = b1[gc1];
    float b2v0 = b2[gc0], b2v1 = b2[gc1];

    // ---- GEMM1: h = ssp(fij @ W1 + b1)  (M=64,N=32/wave,K=64) ----
    f32x4 acc[4][2];
#pragma unroll
    for (int mt = 0; mt < 4; mt++) {
        acc[mt][0] = (f32x4){b1v0, b1v0, b1v0, b1v0};
        acc[mt][1] = (f32x4){b1v1, b1v1, b1v1, b1v1};
    }
#pragma unroll
    for (int kt = 0; kt < 2; kt++) {
        bf16x8 bf0 = *(const bf16x8*)&W1f[((kt * 8 + wid * 2 + 0) * 64 + lane) * 8];
        bf16x8 bf1 = *(const bf16x8*)&W1f[((kt * 8 + wid * 2 + 1) * 64 + lane) * 8];
#pragma unroll
        for (int mt = 0; mt < 4; mt++) {
            const float* ap = fsrc + (size_t)(mt * 16 + rowA) * NS + kt * 32 + kgrp * 8;
            float4 a0 = *(const float4*)ap;
            float4 a1 = *(const float4*)(ap + 4);
            bf16x8 af;
            af[0] = f2bf(a0.x); af[1] = f2bf(a0.y); af[2] = f2bf(a0.z); af[3] = f2bf(a0.w);
            af[4] = f2bf(a1.x); af[5] = f2bf(a1.y); af[6] = f2bf(a1.z); af[7] = f2bf(a1.w);
            acc[mt][0] = __builtin_amdgcn_mfma_f32_16x16x32_bf16(af, bf0, acc[mt][0], 0, 0, 0);
            acc[mt][1] = __builtin_amdgcn_mfma_f32_16x16x32_bf16(af, bf1, acc[mt][1], 0, 0, 0);
        }
    }
    // ssp + store h (bf16) to LDS; C/D layout: col=lane&15, row=(lane>>4)*4+reg
#pragma unroll
    for (int mt = 0; mt < 4; mt++) {
#pragma unroll
        for (int nt = 0; nt < 2; nt++) {
#pragma unroll
            for (int r = 0; r < 4; r++) {
                int row = mt * 16 + kgrp * 4 + r;
                int col = goff + nt * 16 + (lane & 15);
                hL[row * HSTR + col] = f2bf(ssp(acc[mt][nt][r]));
            }
        }
    }
    __syncthreads();

    // ---- GEMM2: Wfilt = h @ W2 + b2  (M=64,N=32/wave,K=128) ----
    f32x4 acc2[4][2];
#pragma unroll
    for (int mt = 0; mt < 4; mt++) {
        acc2[mt][0] = (f32x4){b2v0, b2v0, b2v0, b2v0};
        acc2[mt][1] = (f32x4){b2v1, b2v1, b2v1, b2v1};
    }
#pragma unroll
    for (int kt = 0; kt < 4; kt++) {
        bf16x8 bf0 = *(const bf16x8*)&W2f[((kt * 8 + wid * 2 + 0) * 64 + lane) * 8];
        bf16x8 bf1 = *(const bf16x8*)&W2f[((kt * 8 + wid * 2 + 1) * 64 + lane) * 8];
#pragma unroll
        for (int mt = 0; mt < 4; mt++) {
            bf16x8 af = *(const bf16x8*)&hL[(mt * 16 + rowA) * HSTR + kt * 32 + kgrp * 8];
            acc2[mt][0] = __builtin_amdgcn_mfma_f32_16x16x32_bf16(af, bf0, acc2[mt][0], 0, 0, 0);
            acc2[mt][1] = __builtin_amdgcn_mfma_f32_16x16x32_bf16(af, bf1, acc2[mt][1], 0, 0, 0);
        }
    }
    __syncthreads();   // all waves done reading hL before overwrite

    // masked Wfilt (bf16) -> LDS (reuse hL)
#pragma unroll
    for (int mt = 0; mt < 4; mt++) {
#pragma unroll
        for (int nt = 0; nt < 2; nt++) {
#pragma unroll
            for (int r = 0; r < 4; r++) {
                int row = mt * 16 + kgrp * 4 + r;
                int col = goff + nt * 16 + (lane & 15);
                hL[row * HSTR + col] = f2bf(acc2[mt][nt][r] * mL[row]);
            }
        }
    }
    __syncthreads();

    // ---- gather y rows + reduce over neighbors ----
    int g = t & 127;
    int nh = t >> 7;
    const float* yb = y + (size_t)b * NA * NF;
    float local = 0.0f;
#pragma unroll 8
    for (int i = 0; i < 32; i++) {
        int n = nh * 32 + i;
        float wv = bf2f(hL[n * HSTR + g]);
        local = fmaf(yb[(size_t)iL[n] * NF + g], wv, local);
    }
    red[nh * NF + g] = local;
    __syncthreads();
    if (t < NF) agg[(size_t)ba * NF + t] = red[t] + red[NF + t];
}

// ---------------- kernel 3: out = ssp(agg@Wf2+bf2) @ Wd + bd, in place ----------------
__global__ __launch_bounds__(256) void k_out(float* buf,
                                             const float* __restrict__ Wf2,
                                             const float* __restrict__ bf2,
                                             const float* __restrict__ Wd,
                                             const float* __restrict__ bd) {
    __shared__ float vL[32 * NF];
    int g = threadIdx.x & 127;
    int half = threadIdx.x >> 7;
    int row0 = blockIdx.x * 32 + half * 16;
    float acc[16];

    float bb = bf2[g];
#pragma unroll
    for (int i = 0; i < 16; i++) acc[i] = bb;
    for (int f = 0; f < NF; f += 4) {
        float w0 = Wf2[(f + 0) * NF + g];
        float w1 = Wf2[(f + 1) * NF + g];
        float w2 = Wf2[(f + 2) * NF + g];
        float w3 = Wf2[(f + 3) * NF + g];
#pragma unroll
        for (int i = 0; i < 16; i++) {
            float4 av = *(const float4*)&buf[(size_t)(row0 + i) * NF + f];
            acc[i] = fmaf(av.x, w0, fmaf(av.y, w1, fmaf(av.z, w2, fmaf(av.w, w3, acc[i]))));
        }
    }
#pragma unroll
    for (int i = 0; i < 16; i++) vL[(half * 16 + i) * NF + g] = ssp(acc[i]);
    __syncthreads();

    float bb2 = bd[g];
#pragma unroll
    for (int i = 0; i < 16; i++) acc[i] = bb2;
    for (int f = 0; f < NF; f += 4) {
        float w0 = Wd[(f + 0) * NF + g];
        float w1 = Wd[(f + 1) * NF + g];
        float w2 = Wd[(f + 2) * NF + g];
        float w3 = Wd[(f + 3) * NF + g];
#pragma unroll
        for (int i = 0; i < 16; i++) {
            float4 vv = *(const float4*)&vL[(half * 16 + i) * NF + f];
            acc[i] = fmaf(vv.x, w0, fmaf(vv.y, w1, fmaf(vv.z, w2, fmaf(vv.w, w3, acc[i]))));
        }
    }
#pragma unroll
    for (int i = 0; i < 16; i++) buf[(size_t)(row0 + i) * NF + g] = acc[i];
}

extern "C" void kernel_launch(void* const* d_in, const int* in_sizes, int n_in,
                              void* d_out, int out_size, void* d_ws, size_t ws_size,
                              hipStream_t stream) {
    const float* x    = (const float*)d_in[0];
    const float* rij  = (const float*)d_in[1];
    const float* fij  = (const float*)d_in[2];
    const int*   nbr  = (const int*)d_in[3];
    const int*   nmask = (const int*)d_in[4];     // bool -> int32 per harness
    const float* W_in2f = (const float*)d_in[5];
    const float* W1   = (const float*)d_in[6];
    const float* b1   = (const float*)d_in[7];
    const float* W2   = (const float*)d_in[8];
    const float* b2   = (const float*)d_in[9];
    const float* Wf2  = (const float*)d_in[10];
    const float* bf2  = (const float*)d_in[11];
    const float* Wd   = (const float*)d_in[12];
    const float* bd   = (const float*)d_in[13];

    float* out = (float*)d_out;
    float* y   = (float*)d_ws;                              // 4 MB f32 scratch
    short* W1f = (short*)((char*)d_ws + (size_t)NB * NA * NF * 4);   // 16 KB
    short* W2f = W1f + NS * NF;                                      // 32 KB

    const int rows = NB * NA;   // 8192

    k_prep<<<64, 256, 0, stream>>>(W1, W2, W1f, W2f);
    k_in2f<<<rows / 32, 256, 0, stream>>>(x, W_in2f, y);
    k_conv<<<rows, 256, 0, stream>>>(fij, rij, nbr, nmask, y, W1f, b1, W2f, b2, out);
    k_out<<<rows / 32, 256, 0, stream>>>(out, Wf2, bf2, Wd, bd);
}

// Round 4
// 125.808 us; speedup vs baseline: 3.8852x; 1.2437x over previous
//
#include <hip/hip_runtime.h>
#include <math.h>

#define NB 8
#define NA 1024
#define NN 64
#define NF 128
#define NS 64
#define LN2 0.69314718055994530942f
#define HSTR 136   // h (bf16) LDS row stride in elems: 272B rows, balanced b128 reads
#define WSTR 130   // Wfilt (f32) LDS row stride in elems: bank-balanced writes/reads

typedef __attribute__((ext_vector_type(8))) short bf16x8;
typedef __attribute__((ext_vector_type(4))) float f32x4;

__device__ __forceinline__ float ssp(float x) {
    return fmaxf(x, 0.0f) + __logf(1.0f + __expf(-fabsf(x))) - LN2;
}
__device__ __forceinline__ short f2bf(float f) {      // RNE f32 -> bf16
    unsigned u = __float_as_uint(f);
    u += 0x7fffu + ((u >> 16) & 1u);
    return (short)(u >> 16);
}

// ---------------- prep: swizzle W1,W2 into MFMA B-fragment order (bf16) ----------------
__global__ __launch_bounds__(256) void k_prep(const float* __restrict__ W1,
                                              const float* __restrict__ W2,
                                              short* __restrict__ W1f,
                                              short* __restrict__ W2f) {
    int t = blockIdx.x * 256 + threadIdx.x;
    if (t < NS * NF) {
        int k = t >> 7, n = t & 127;
        int kt = k >> 5, lg = (k >> 3) & 3, j = k & 7, ntg = n >> 4, col = n & 15;
        W1f[((kt * 8 + ntg) * 64 + (lg * 16 + col)) * 8 + j] = f2bf(W1[t]);
    }
    if (t < NF * NF) {
        int k = t >> 7, n = t & 127;
        int kt = k >> 5, lg = (k >> 3) & 3, j = k & 7, ntg = n >> 4, col = n & 15;
        W2f[((kt * 8 + ntg) * 64 + (lg * 16 + col)) * 8 + j] = f2bf(W2[t]);
    }
}

// ---------------- kernel 1: y = x @ W_in2f (no bias), f32 ----------------
__global__ __launch_bounds__(256) void k_in2f(const float* __restrict__ x,
                                              const float* __restrict__ W,
                                              float* __restrict__ y) {
    int g = threadIdx.x & 127;
    int half = threadIdx.x >> 7;
    int row0 = blockIdx.x * 32 + half * 16;
    float acc[16];
#pragma unroll
    for (int i = 0; i < 16; i++) acc[i] = 0.0f;
    for (int k = 0; k < NF; k += 4) {
        float w0 = W[(k + 0) * NF + g];
        float w1 = W[(k + 1) * NF + g];
        float w2 = W[(k + 2) * NF + g];
        float w3 = W[(k + 3) * NF + g];
#pragma unroll
        for (int i = 0; i < 16; i++) {
            float4 xv = *(const float4*)&x[(size_t)(row0 + i) * NF + k];
            acc[i] = fmaf(xv.x, w0, fmaf(xv.y, w1, fmaf(xv.z, w2, fmaf(xv.w, w3, acc[i]))));
        }
    }
#pragma unroll
    for (int i = 0; i < 16; i++) y[(size_t)(row0 + i) * NF + g] = acc[i];
}

// ---------------- kernel 2: MFMA filter net + cfconv aggregation ----------------
// one block per (b,a); 4 waves, wave wid owns g-slice [wid*32, wid*32+32)
// LDS phase overlay: {fijL 8K | hL 17.4K} -> {wfL 33.3K}
__global__ __launch_bounds__(256) void k_conv(
        const float* __restrict__ fij, const float* __restrict__ rij,
        const int* __restrict__ nbr, const int* __restrict__ nmask,
        const float* __restrict__ y,
        const short* __restrict__ W1f, const float* __restrict__ b1,
        const short* __restrict__ W2f, const float* __restrict__ b2,
        float* __restrict__ agg) {
    __shared__ __align__(16) char smem[NN * WSTR * 4];   // 33280 B union
    __shared__ float mL[NN];
    __shared__ int   iL[NN];
    __shared__ float red[2 * NF];

    short* hL  = (short*)(smem + NN * NS * 2);   // after 8K fijL region
    float* wfL = (float*)smem;

    int t = threadIdx.x;
    int ba = blockIdx.x;
    int b = ba >> 10;
    int lane = t & 63;
    int wid = t >> 6;

    const float* fsrc = fij + (size_t)ba * NN * NS;

    // ---- stage f_ij tile as bf16 into fijL (XOR-swizzled), each elem converted once ----
    {
        int row = t >> 2;            // 0..63
        int k0 = (t & 3) * 16;       // 0,16,32,48
        const float4* src = (const float4*)(fsrc + row * NS + k0);
        float4 a = src[0], bb = src[1], c = src[2], d = src[3];
        bf16x8 lo, hi;
        lo[0] = f2bf(a.x);  lo[1] = f2bf(a.y);  lo[2] = f2bf(a.z);  lo[3] = f2bf(a.w);
        lo[4] = f2bf(bb.x); lo[5] = f2bf(bb.y); lo[6] = f2bf(bb.z); lo[7] = f2bf(bb.w);
        hi[0] = f2bf(c.x);  hi[1] = f2bf(c.y);  hi[2] = f2bf(c.z);  hi[3] = f2bf(c.w);
        hi[4] = f2bf(d.x);  hi[5] = f2bf(d.y);  hi[6] = f2bf(d.z);  hi[7] = f2bf(d.w);
        int base = row * 128 + k0 * 2;
        int sw = (row & 7) << 4;
        *(bf16x8*)(smem + ((base) ^ sw))      = lo;
        *(bf16x8*)(smem + ((base + 16) ^ sw)) = hi;
    }
    if (t < NN) {
        float r = rij[(size_t)ba * NN + t];
        int mk = nmask[(size_t)ba * NN + t];
        mL[t] = (mk != 0 && r <= 5.0f) ? 1.0f : 0.0f;
        iL[t] = nbr[(size_t)ba * NN + t];
    }
    __syncthreads();

    int rowA = lane & 15;
    int kgrp = lane >> 4;
    int goff = wid * 32;

    int gc0 = goff + (lane & 15);
    int gc1 = gc0 + 16;
    float b1v0 = b1[gc0], b1v1 = b1[gc1];
    float b2v0 = b2[gc0], b2v1 = b2[gc1];

    // ---- GEMM1: h = ssp(fij @ W1 + b1)  (M=64, N=32/wave, K=64) ----
    f32x4 acc[4][2];
#pragma unroll
    for (int mt = 0; mt < 4; mt++) {
        acc[mt][0] = (f32x4){b1v0, b1v0, b1v0, b1v0};
        acc[mt][1] = (f32x4){b1v1, b1v1, b1v1, b1v1};
    }
#pragma unroll
    for (int kt = 0; kt < 2; kt++) {
        bf16x8 bf0 = *(const bf16x8*)&W1f[((kt * 8 + wid * 2 + 0) * 64 + lane) * 8];
        bf16x8 bf1 = *(const bf16x8*)&W1f[((kt * 8 + wid * 2 + 1) * 64 + lane) * 8];
#pragma unroll
        for (int mt = 0; mt < 4; mt++) {
            int row = mt * 16 + rowA;
            int byte = (row * 128 + kt * 64 + kgrp * 16) ^ ((row & 7) << 4);
            bf16x8 af = *(const bf16x8*)(smem + byte);
            acc[mt][0] = __builtin_amdgcn_mfma_f32_16x16x32_bf16(af, bf0, acc[mt][0], 0, 0, 0);
            acc[mt][1] = __builtin_amdgcn_mfma_f32_16x16x32_bf16(af, bf1, acc[mt][1], 0, 0, 0);
        }
    }
    // ssp + store h (bf16) to hL; C/D layout: col=lane&15, row=(lane>>4)*4+reg
#pragma unroll
    for (int mt = 0; mt < 4; mt++) {
#pragma unroll
        for (int nt = 0; nt < 2; nt++) {
#pragma unroll
            for (int r = 0; r < 4; r++) {
                int row = mt * 16 + kgrp * 4 + r;
                int col = goff + nt * 16 + (lane & 15);
                hL[row * HSTR + col] = f2bf(ssp(acc[mt][nt][r]));
            }
        }
    }
    __syncthreads();

    // ---- GEMM2: Wfilt = h @ W2 + b2  (M=64, N=32/wave, K=128) ----
    f32x4 acc2[4][2];
#pragma unroll
    for (int mt = 0; mt < 4; mt++) {
        acc2[mt][0] = (f32x4){b2v0, b2v0, b2v0, b2v0};
        acc2[mt][1] = (f32x4){b2v1, b2v1, b2v1, b2v1};
    }
#pragma unroll
    for (int kt = 0; kt < 4; kt++) {
        bf16x8 bf0 = *(const bf16x8*)&W2f[((kt * 8 + wid * 2 + 0) * 64 + lane) * 8];
        bf16x8 bf1 = *(const bf16x8*)&W2f[((kt * 8 + wid * 2 + 1) * 64 + lane) * 8];
#pragma unroll
        for (int mt = 0; mt < 4; mt++) {
            bf16x8 af = *(const bf16x8*)&hL[(mt * 16 + rowA) * HSTR + kt * 32 + kgrp * 8];
            acc2[mt][0] = __builtin_amdgcn_mfma_f32_16x16x32_bf16(af, bf0, acc2[mt][0], 0, 0, 0);
            acc2[mt][1] = __builtin_amdgcn_mfma_f32_16x16x32_bf16(af, bf1, acc2[mt][1], 0, 0, 0);
        }
    }
    __syncthreads();   // hL dead; wfL may overwrite the union

    // masked Wfilt (f32) -> wfL
#pragma unroll
    for (int mt = 0; mt < 4; mt++) {
#pragma unroll
        for (int nt = 0; nt < 2; nt++) {
#pragma unroll
            for (int r = 0; r < 4; r++) {
                int row = mt * 16 + kgrp * 4 + r;
                int col = goff + nt * 16 + (lane & 15);
                wfL[row * WSTR + col] = acc2[mt][nt][r] * mL[row];
            }
        }
    }
    __syncthreads();

    // ---- gather y rows + reduce over neighbors ----
    int g = t & 127;
    int nh = t >> 7;
    const float* yb = y + (size_t)b * NA * NF;
    float local = 0.0f;
#pragma unroll 8
    for (int i = 0; i < 32; i++) {
        int n = nh * 32 + i;
        float wv = wfL[n * WSTR + g];
        local = fmaf(yb[(size_t)iL[n] * NF + g], wv, local);
    }
    red[nh * NF + g] = local;
    __syncthreads();
    if (t < NF) agg[(size_t)ba * NF + t] = red[t] + red[NF + t];
}

// ---------------- kernel 3: out = ssp(agg@Wf2+bf2) @ Wd + bd, in place ----------------
__global__ __launch_bounds__(256) void k_out(float* buf,
                                             const float* __restrict__ Wf2,
                                             const float* __restrict__ bf2,
                                             const float* __restrict__ Wd,
                                             const float* __restrict__ bd) {
    __shared__ float vL[32 * NF];
    int g = threadIdx.x & 127;
    int half = threadIdx.x >> 7;
    int row0 = blockIdx.x * 32 + half * 16;
    float acc[16];

    float bb = bf2[g];
#pragma unroll
    for (int i = 0; i < 16; i++) acc[i] = bb;
    for (int f = 0; f < NF; f += 4) {
        float w0 = Wf2[(f + 0) * NF + g];
        float w1 = Wf2[(f + 1) * NF + g];
        float w2 = Wf2[(f + 2) * NF + g];
        float w3 = Wf2[(f + 3) * NF + g];
#pragma unroll
        for (int i = 0; i < 16; i++) {
            float4 av = *(const float4*)&buf[(size_t)(row0 + i) * NF + f];
            acc[i] = fmaf(av.x, w0, fmaf(av.y, w1, fmaf(av.z, w2, fmaf(av.w, w3, acc[i]))));
        }
    }
#pragma unroll
    for (int i = 0; i < 16; i++) vL[(half * 16 + i) * NF + g] = ssp(acc[i]);
    __syncthreads();

    float bb2 = bd[g];
#pragma unroll
    for (int i = 0; i < 16; i++) acc[i] = bb2;
    for (int f = 0; f < NF; f += 4) {
        float w0 = Wd[(f + 0) * NF + g];
        float w1 = Wd[(f + 1) * NF + g];
        float w2 = Wd[(f + 2) * NF + g];
        float w3 = Wd[(f + 3) * NF + g];
#pragma unroll
        for (int i = 0; i < 16; i++) {
            float4 vv = *(const float4*)&vL[(half * 16 + i) * NF + f];
            acc[i] = fmaf(vv.x, w0, fmaf(vv.y, w1, fmaf(vv.z, w2, fmaf(vv.w, w3, acc[i]))));
        }
    }
#pragma unroll
    for (int i = 0; i < 16; i++) buf[(size_t)(row0 + i) * NF + g] = acc[i];
}

extern "C" void kernel_launch(void* const* d_in, const int* in_sizes, int n_in,
                              void* d_out, int out_size, void* d_ws, size_t ws_size,
                              hipStream_t stream) {
    const float* x    = (const float*)d_in[0];
    const float* rij  = (const float*)d_in[1];
    const float* fij  = (const float*)d_in[2];
    const int*   nbr  = (const int*)d_in[3];
    const int*   nmask = (const int*)d_in[4];     // bool -> int32 per harness
    const float* W_in2f = (const float*)d_in[5];
    const float* W1   = (const float*)d_in[6];
    const float* b1   = (const float*)d_in[7];
    const float* W2   = (const float*)d_in[8];
    const float* b2   = (const float*)d_in[9];
    const float* Wf2  = (const float*)d_in[10];
    const float* bf2  = (const float*)d_in[11];
    const float* Wd   = (const float*)d_in[12];
    const float* bd   = (const float*)d_in[13];

    float* out = (float*)d_out;
    float* y   = (float*)d_ws;                              // 4 MB f32 scratch
    short* W1f = (short*)((char*)d_ws + (size_t)NB * NA * NF * 4);   // 16 KB
    short* W2f = W1f + NS * NF;                                      // 32 KB

    const int rows = NB * NA;   // 8192

    k_prep<<<64, 256, 0, stream>>>(W1, W2, W1f, W2f);
    k_in2f<<<rows / 32, 256, 0, stream>>>(x, W_in2f, y);
    k_conv<<<rows, 256, 0, stream>>>(fij, rij, nbr, nmask, y, W1f, b1, W2f, b2, out);
    k_out<<<rows / 32, 256, 0, stream>>>(out, Wf2, bf2, Wd, bd);
}

// Round 6
// 123.467 us; speedup vs baseline: 3.9589x; 1.0190x over previous
//
#include <hip/hip_runtime.h>
#include <math.h>

#define NB 8
#define NA 1024
#define NN 64
#define NF 128
#define NS 64
#define LN2 0.69314718055994530942f
#define HSTR 136   // h (bf16) LDS row stride in elems: 272B rows, balanced b128 reads
#define WSTR 130   // Wfilt (f32) LDS row stride in elems: bank-balanced writes/reads

typedef __attribute__((ext_vector_type(8))) short bf16x8;
typedef __attribute__((ext_vector_type(4))) float f32x4;
typedef __attribute__((ext_vector_type(4))) unsigned u32x4;

__device__ __forceinline__ float ssp(float x) {
    return fmaxf(x, 0.0f) + __logf(1.0f + __expf(-fabsf(x))) - LN2;
}
__device__ __forceinline__ short f2bf(float f) {      // RNE f32 -> bf16
    unsigned u = __float_as_uint(f);
    u += 0x7fffu + ((u >> 16) & 1u);
    return (short)(u >> 16);
}
__device__ __forceinline__ unsigned pkbf(float a, float b) {   // packed RNE pair
    return ((unsigned)(unsigned short)f2bf(b) << 16) | (unsigned)(unsigned short)f2bf(a);
}

// ---------------- prep: swizzle W1,W2 into MFMA B-fragment order (bf16) ----------------
__global__ __launch_bounds__(256) void k_prep(const float* __restrict__ W1,
                                              const float* __restrict__ W2,
                                              short* __restrict__ W1f,
                                              short* __restrict__ W2f) {
    int t = blockIdx.x * 256 + threadIdx.x;
    if (t < NS * NF) {
        int k = t >> 7, n = t & 127;
        int kt = k >> 5, lg = (k >> 3) & 3, j = k & 7, ntg = n >> 4, col = n & 15;
        W1f[((kt * 8 + ntg) * 64 + (lg * 16 + col)) * 8 + j] = f2bf(W1[t]);
    }
    if (t < NF * NF) {
        int k = t >> 7, n = t & 127;
        int kt = k >> 5, lg = (k >> 3) & 3, j = k & 7, ntg = n >> 4, col = n & 15;
        W2f[((kt * 8 + ntg) * 64 + (lg * 16 + col)) * 8 + j] = f2bf(W2[t]);
    }
}

// ---------------- kernel 1: y = x @ W_in2f (no bias), f32 ----------------
__global__ __launch_bounds__(256) void k_in2f(const float* __restrict__ x,
                                              const float* __restrict__ W,
                                              float* __restrict__ y) {
    int g = threadIdx.x & 127;
    int half = threadIdx.x >> 7;
    int row0 = blockIdx.x * 32 + half * 16;
    float acc[16];
#pragma unroll
    for (int i = 0; i < 16; i++) acc[i] = 0.0f;
    for (int k = 0; k < NF; k += 4) {
        float w0 = W[(k + 0) * NF + g];
        float w1 = W[(k + 1) * NF + g];
        float w2 = W[(k + 2) * NF + g];
        float w3 = W[(k + 3) * NF + g];
#pragma unroll
        for (int i = 0; i < 16; i++) {
            float4 xv = *(const float4*)&x[(size_t)(row0 + i) * NF + k];
            acc[i] = fmaf(xv.x, w0, fmaf(xv.y, w1, fmaf(xv.z, w2, fmaf(xv.w, w3, acc[i]))));
        }
    }
#pragma unroll
    for (int i = 0; i < 16; i++) y[(size_t)(row0 + i) * NF + g] = acc[i];
}

// ---------------- kernel 2: MFMA filter net + cfconv with valid-row compaction ----------------
// one block per (b,a); 4 waves, wave wid owns g-slice [wid*32, wid*32+32)
// LDS phase overlay: {fijL 8K | hL 17.4K} -> {wfL 33.3K}
__global__ __launch_bounds__(256) void k_conv(
        const float* __restrict__ fij, const float* __restrict__ rij,
        const int* __restrict__ nbr, const int* __restrict__ nmask,
        const float* __restrict__ y,
        const short* __restrict__ W1f, const float* __restrict__ b1,
        const short* __restrict__ W2f, const float* __restrict__ b2,
        float* __restrict__ agg) {
    __shared__ __align__(16) char smem[NN * WSTR * 4];   // 33280 B union
    __shared__ int  cIdx[NN];     // compacted source row (neighbor slot)
    __shared__ int  cGat[NN];     // compacted neighbor atom index
    __shared__ int  vCnt;
    __shared__ float red[2 * NF];

    short* hL  = (short*)(smem + NN * NS * 2);   // after 8K fijL region
    float* wfL = (float*)smem;

    int t = threadIdx.x;
    int ba = blockIdx.x;
    int b = ba >> 10;
    int lane = t & 63;
    int wid = t >> 6;

    const float* fsrc = fij + (size_t)ba * NN * NS;

    // ---- phase 0: wave 0 scans the mask, builds compacted row list ----
    if (t < NN) {
        float r = rij[(size_t)ba * NN + t];
        int mk = nmask[(size_t)ba * NN + t];
        int nb = nbr[(size_t)ba * NN + t];
        bool valid = (mk != 0) && (r <= 5.0f);
        unsigned long long bal = __ballot(valid);
        int pos = __popcll(bal & ((1ULL << t) - 1ULL));
        if (valid) { cIdx[pos] = t; cGat[pos] = nb; }
        if (t == 0) vCnt = (int)__popcll(bal);
    }
    __syncthreads();
    int V = vCnt;
    int MT = (V + 15) >> 4;       // M-tiles of 16 rows (0..4)

    // ---- stage compacted f_ij rows as bf16 into fijL (XOR-swizzled) ----
    {
        int j = t >> 2;                     // dest row 0..63
        if (j < MT * 16) {
            int k0 = (t & 3) * 16;
            u32x4 lo = (u32x4){0, 0, 0, 0}, hi = (u32x4){0, 0, 0, 0};
            if (j < V) {
                const float4* src = (const float4*)(fsrc + (size_t)cIdx[j] * NS + k0);
                float4 a = src[0], bb = src[1], c = src[2], d = src[3];
                lo = (u32x4){pkbf(a.x, a.y), pkbf(a.z, a.w), pkbf(bb.x, bb.y), pkbf(bb.z, bb.w)};
                hi = (u32x4){pkbf(c.x, c.y), pkbf(c.z, c.w), pkbf(d.x, d.y), pkbf(d.z, d.w)};
            }
            int base = j * 128 + k0 * 2;
            int sw = (j & 7) << 4;
            *(u32x4*)(smem + ((base) ^ sw))      = lo;
            *(u32x4*)(smem + ((base + 16) ^ sw)) = hi;
        }
    }
    __syncthreads();

    int rowA = lane & 15;
    int kgrp = lane >> 4;
    int goff = wid * 32;

    int gc0 = goff + (lane & 15);
    int gc1 = gc0 + 16;
    float b1v0 = b1[gc0], b1v1 = b1[gc1];
    float b2v0 = b2[gc0], b2v1 = b2[gc1];

    // ---- GEMM1: h = ssp(fij_c @ W1 + b1)  (M=MT*16, N=32/wave, K=64) ----
    f32x4 acc[4][2];
#pragma unroll
    for (int mt = 0; mt < 4; mt++) {
        acc[mt][0] = (f32x4){b1v0, b1v0, b1v0, b1v0};
        acc[mt][1] = (f32x4){b1v1, b1v1, b1v1, b1v1};
    }
#pragma unroll
    for (int kt = 0; kt < 2; kt++) {
        bf16x8 bf0 = *(const bf16x8*)&W1f[((kt * 8 + wid * 2 + 0) * 64 + lane) * 8];
        bf16x8 bf1 = *(const bf16x8*)&W1f[((kt * 8 + wid * 2 + 1) * 64 + lane) * 8];
#pragma unroll
        for (int mt = 0; mt < 4; mt++) {
            if (mt < MT) {
                int row = mt * 16 + rowA;
                int byte = (row * 128 + kt * 64 + kgrp * 16) ^ ((row & 7) << 4);
                bf16x8 af = *(const bf16x8*)(smem + byte);
                acc[mt][0] = __builtin_amdgcn_mfma_f32_16x16x32_bf16(af, bf0, acc[mt][0], 0, 0, 0);
                acc[mt][1] = __builtin_amdgcn_mfma_f32_16x16x32_bf16(af, bf1, acc[mt][1], 0, 0, 0);
            }
        }
    }
    // ssp + store h (bf16) to hL; C/D layout: col=lane&15, row=(lane>>4)*4+reg
#pragma unroll
    for (int mt = 0; mt < 4; mt++) {
        if (mt < MT) {
#pragma unroll
            for (int nt = 0; nt < 2; nt++) {
                int col = goff + nt * 16 + (lane & 15);
                int row0 = mt * 16 + kgrp * 4;
                unsigned p01 = pkbf(ssp(acc[mt][nt][0]), ssp(acc[mt][nt][1]));
                unsigned p23 = pkbf(ssp(acc[mt][nt][2]), ssp(acc[mt][nt][3]));
                hL[(row0 + 0) * HSTR + col] = (short)(p01 & 0xffffu);
                hL[(row0 + 1) * HSTR + col] = (short)(p01 >> 16);
                hL[(row0 + 2) * HSTR + col] = (short)(p23 & 0xffffu);
                hL[(row0 + 3) * HSTR + col] = (short)(p23 >> 16);
            }
        }
    }
    __syncthreads();

    // ---- GEMM2: Wfilt = h @ W2 + b2  (M=MT*16, N=32/wave, K=128) ----
    f32x4 acc2[4][2];
#pragma unroll
    for (int mt = 0; mt < 4; mt++) {
        acc2[mt][0] = (f32x4){b2v0, b2v0, b2v0, b2v0};
        acc2[mt][1] = (f32x4){b2v1, b2v1, b2v1, b2v1};
    }
#pragma unroll
    for (int kt = 0; kt < 4; kt++) {
        bf16x8 bf0 = *(const bf16x8*)&W2f[((kt * 8 + wid * 2 + 0) * 64 + lane) * 8];
        bf16x8 bf1 = *(const bf16x8*)&W2f[((kt * 8 + wid * 2 + 1) * 64 + lane) * 8];
#pragma unroll
        for (int mt = 0; mt < 4; mt++) {
            if (mt < MT) {
                bf16x8 af = *(const bf16x8*)&hL[(mt * 16 + rowA) * HSTR + kt * 32 + kgrp * 8];
                acc2[mt][0] = __builtin_amdgcn_mfma_f32_16x16x32_bf16(af, bf0, acc2[mt][0], 0, 0, 0);
                acc2[mt][1] = __builtin_amdgcn_mfma_f32_16x16x32_bf16(af, bf1, acc2[mt][1], 0, 0, 0);
            }
        }
    }
    __syncthreads();   // hL dead; wfL may overwrite the union

    // Wfilt (f32) -> wfL (no mask multiply: all compacted rows valid)
#pragma unroll
    for (int mt = 0; mt < 4; mt++) {
        if (mt < MT) {
#pragma unroll
            for (int nt = 0; nt < 2; nt++) {
#pragma unroll
                for (int r = 0; r < 4; r++) {
                    int row = mt * 16 + kgrp * 4 + r;
                    int col = goff + nt * 16 + (lane & 15);
                    wfL[row * WSTR + col] = acc2[mt][nt][r];
                }
            }
        }
    }
    __syncthreads();

    // ---- gather y rows + reduce over valid neighbors (interleaved halves) ----
    int g = t & 127;
    int nh = t >> 7;
    const float* yb = y + (size_t)b * NA * NF;
    float local = 0.0f;
#pragma unroll 4
    for (int j = nh; j < V; j += 2) {
        float wv = wfL[j * WSTR + g];
        local = fmaf(yb[(size_t)cGat[j] * NF + g], wv, local);
    }
    red[nh * NF + g] = local;
    __syncthreads();
    if (t < NF) agg[(size_t)ba * NF + t] = red[t] + red[NF + t];
}

// ---------------- kernel 3: out = ssp(agg@Wf2+bf2) @ Wd + bd, in place ----------------
__global__ __launch_bounds__(256) void k_out(float* buf,
                                             const float* __restrict__ Wf2,
                                             const float* __restrict__ bf2,
                                             const float* __restrict__ Wd,
                                             const float* __restrict__ bd) {
    __shared__ float vL[32 * NF];
    int g = threadIdx.x & 127;
    int half = threadIdx.x >> 7;
    int row0 = blockIdx.x * 32 + half * 16;
    float acc[16];

    float bb = bf2[g];
#pragma unroll
    for (int i = 0; i < 16; i++) acc[i] = bb;
    for (int f = 0; f < NF; f += 4) {
        float w0 = Wf2[(f + 0) * NF + g];
        float w1 = Wf2[(f + 1) * NF + g];
        float w2 = Wf2[(f + 2) * NF + g];
        float w3 = Wf2[(f + 3) * NF + g];
#pragma unroll
        for (int i = 0; i < 16; i++) {
            float4 av = *(const float4*)&buf[(size_t)(row0 + i) * NF + f];
            acc[i] = fmaf(av.x, w0, fmaf(av.y, w1, fmaf(av.z, w2, fmaf(av.w, w3, acc[i]))));
        }
    }
#pragma unroll
    for (int i = 0; i < 16; i++) vL[(half * 16 + i) * NF + g] = ssp(acc[i]);
    __syncthreads();

    float bb2 = bd[g];
#pragma unroll
    for (int i = 0; i < 16; i++) acc[i] = bb2;
    for (int f = 0; f < NF; f += 4) {
        float w0 = Wd[(f + 0) * NF + g];
        float w1 = Wd[(f + 1) * NF + g];
        float w2 = Wd[(f + 2) * NF + g];
        float w3 = Wd[(f + 3) * NF + g];
#pragma unroll
        for (int i = 0; i < 16; i++) {
            float4 vv = *(const float4*)&vL[(half * 16 + i) * NF + f];
            acc[i] = fmaf(vv.x, w0, fmaf(vv.y, w1, fmaf(vv.z, w2, fmaf(vv.w, w3, acc[i]))));
        }
    }
#pragma unroll
    for (int i = 0; i < 16; i++) buf[(size_t)(row0 + i) * NF + g] = acc[i];
}

extern "C" void kernel_launch(void* const* d_in, const int* in_sizes, int n_in,
                              void* d_out, int out_size, void* d_ws, size_t ws_size,
                              hipStream_t stream) {
    const float* x    = (const float*)d_in[0];
    const float* rij  = (const float*)d_in[1];
    const float* fij  = (const float*)d_in[2];
    const int*   nbr  = (const int*)d_in[3];
    const int*   nmask = (const int*)d_in[4];     // bool -> int32 per harness
    const float* W_in2f = (const float*)d_in[5];
    const float* W1   = (const float*)d_in[6];
    const float* b1   = (const float*)d_in[7];
    const float* W2   = (const float*)d_in[8];
    const float* b2   = (const float*)d_in[9];
    const float* Wf2  = (const float*)d_in[10];
    const float* bf2  = (const float*)d_in[11];
    const float* Wd   = (const float*)d_in[12];
    const float* bd   = (const float*)d_in[13];

    float* out = (float*)d_out;
    float* y   = (float*)d_ws;                              // 4 MB f32 scratch
    short* W1f = (short*)((char*)d_ws + (size_t)NB * NA * NF * 4);   // 16 KB
    short* W2f = W1f + NS * NF;                                      // 32 KB

    const int rows = NB * NA;   // 8192

    k_prep<<<64, 256, 0, stream>>>(W1, W2, W1f, W2f);
    k_in2f<<<rows / 32, 256, 0, stream>>>(x, W_in2f, y);
    k_conv<<<rows, 256, 0, stream>>>(fij, rij, nbr, nmask, y, W1f, b1, W2f, b2, out);
    k_out<<<rows / 32, 256, 0, stream>>>(out, Wf2, bf2, Wd, bd);
}